// Round 13
// baseline (343.282 us; speedup 1.0000x reference)
//
#include <hip/hip_runtime.h>

// 2-layer fused LSTM + linear head.  B=8192, T=128, D=32, H=64, gates=256.
// R13 = R5 structure with the allocator UNCONSTRAINED (R5's failure was
// __launch_bounds__(1024,8) forcing VGPR 32 -> thrash; HW gives 8 waves/SIMD
// automatically when VGPR <= 64).  1024 thr / 16 waves, BT=16, grid 512 ->
// 2 blocks/CU = 32 waves/CU target.  Wave wv owns h-slice [4wv,4wv+4):
// 7 MFMAs + 2 elems/lane per step (~300cy VALU) -> same total VALU as R4 at
// 2x the TLP, so per-wave chain latency (the ~45% idle R7/R9/R10/R11/R12
// all failed to fill by scheduling) is hidden by wave count instead.
// VGPR diet (target <=64): biases in VGPR (8), NO x-prefetch (R6: neutral),
// no setprio (R9: neutral).  Gate-interleaved row-tile per layer:
//   A-row (lane bl): gate = bl&3, h = 4wv + (bl>>2)
//   D element r of lane (bl,kg): gate r of h = 4wv+kg  (all 4 gates/lane)
// log2e folded into weights (i,f,o x1.4427; g x2.8854); merged-rcp gate math
// = 5 exp2 + 2 rcp = 7 hw trans/element.

#define TT  128
#define DIN 32
#define BT  16
#define L2E 1.44269504088896340736f

typedef _Float16 h8 __attribute__((ext_vector_type(8)));
typedef __fp16   p2 __attribute__((ext_vector_type(2)));
typedef float    f4 __attribute__((ext_vector_type(4)));

#define MFMA(A, B, C) __builtin_amdgcn_mfma_f32_16x16x32_f16((A), (B), (C), 0, 0, 0)

__device__ __forceinline__ h8 cvt8s(const float* p, float s) {
    float4 a = *(const float4*)p;
    float4 b = *(const float4*)(p + 4);
    union { h8 v; p2 q[4]; } u;
    u.q[0] = __builtin_amdgcn_cvt_pkrtz(a.x * s, a.y * s);
    u.q[1] = __builtin_amdgcn_cvt_pkrtz(a.z * s, a.w * s);
    u.q[2] = __builtin_amdgcn_cvt_pkrtz(b.x * s, b.y * s);
    u.q[3] = __builtin_amdgcn_cvt_pkrtz(b.z * s, b.w * s);
    return u.v;
}

__device__ __forceinline__ h8 cvt8(const float* p) {
    float4 a = *(const float4*)p;
    float4 b = *(const float4*)(p + 4);
    union { h8 v; p2 q[4]; } u;
    u.q[0] = __builtin_amdgcn_cvt_pkrtz(a.x, a.y);
    u.q[1] = __builtin_amdgcn_cvt_pkrtz(a.z, a.w);
    u.q[2] = __builtin_amdgcn_cvt_pkrtz(b.x, b.y);
    u.q[3] = __builtin_amdgcn_cvt_pkrtz(b.z, b.w);
    return u.v;
}

// acc = {yi', yf', yg'(2x-scaled), yo'} (log2e pre-folded); updates c, returns h.
__device__ __forceinline__ float elem(const f4& acc, float& c) {
    float Ei = __builtin_amdgcn_exp2f(-acc[0]);
    float Ef = __builtin_amdgcn_exp2f(-acc[1]);
    float Eg = __builtin_amdgcn_exp2f(-acc[2]);
    float Eo = __builtin_amdgcn_exp2f(-acc[3]);
    float a = 1.f + Ei, b = 1.f + Eg, d = 1.f + Ef;
    float P = a * b;
    float N = c * P + (1.f - Eg) * d;
    c = N * __builtin_amdgcn_rcpf(P * d);
    float Ec = __builtin_amdgcn_exp2f(-2.f * L2E * c);
    return (1.f - Ec) * __builtin_amdgcn_rcpf((1.f + Ec) * (1.f + Eo));
}

__global__ __launch_bounds__(1024, 4)
void lstm2_fused(const float* __restrict__ x,
                 const float* __restrict__ wih0, const float* __restrict__ whh0,
                 const float* __restrict__ bih0, const float* __restrict__ bhh0,
                 const float* __restrict__ wih1, const float* __restrict__ whh1,
                 const float* __restrict__ bih1, const float* __restrict__ bhh1,
                 const float* __restrict__ fcw,  const float* __restrict__ fcb,
                 float* __restrict__ out)
{
    const int tid  = threadIdx.x;
    const int lane = tid & 63;
    const int wv   = tid >> 6;      // 0..15 -> h slice [4wv, 4wv+4)
    const int bl   = lane & 15;
    const int kg   = lane >> 4;

    __shared__ alignas(16) unsigned short hb[2][2][BT * 64];  // 8 KB
    __shared__ float wpart[16][BT];                           // 1 KB

    for (int i = tid; i < (int)(sizeof(hb) / 4); i += 1024) ((int*)hb)[i] = 0;

    // ---- weights + biases: one gate-interleaved tile per layer (VGPR) ----
    h8 W0[3], W1[4];
    f4 b0v, b1v;
    {
        const int gam = bl & 3;
        const int g   = 64 * gam + 4 * wv + (bl >> 2);
        const float sc = (gam == 2) ? 2.f * L2E : L2E;
        W0[0] = cvt8s(wih0 + g * 32 + 8 * kg, sc);
        W0[1] = cvt8s(whh0 + g * 64 + 8 * kg, sc);
        W0[2] = cvt8s(whh0 + g * 64 + 32 + 8 * kg, sc);
        W1[0] = cvt8s(wih1 + g * 64 + 8 * kg, sc);
        W1[1] = cvt8s(wih1 + g * 64 + 32 + 8 * kg, sc);
        W1[2] = cvt8s(whh1 + g * 64 + 8 * kg, sc);
        W1[3] = cvt8s(whh1 + g * 64 + 32 + 8 * kg, sc);
        #pragma unroll
        for (int r = 0; r < 4; ++r) {
            const int gr = 64 * r + 4 * wv + kg;     // D element r = gate r of h=4wv+kg
            const float scr = (r == 2) ? 2.f * L2E : L2E;
            b0v[r] = (bih0[gr] + bhh0[gr]) * scr;
            b1v[r] = (bih1[gr] + bhh1[gr]) * scr;
        }
    }

    const int bbase = blockIdx.x * BT;
    const float* xp = x + (size_t)(bbase + bl) * (TT * DIN) + 8 * kg;

    float c0 = 0.f, c1 = 0.f, h1f = 0.f;

    const int swz = (bl & 7) << 4;
    char* lb = (char*)hb;
    const int rowoff = bl * 128;
    const int rd0 = rowoff + ((16 * kg) ^ swz);
    const int rd1 = rowoff + ((64 + 16 * kg) ^ swz);
    const int wro = rowoff + ((8 * wv + 2 * kg) ^ swz);   // h = 4wv+kg (2B store)

    __syncthreads();   // LDS zero visible

    // ---- it = 0: L0 only; h0[-1] = 0 from zeroed parity-1 buffer ----
    {
        h8 xc  = cvt8(xp);
        h8 hr0 = *(const h8*)(lb + 2048 + rd0);
        h8 hr1 = *(const h8*)(lb + 2048 + rd1);
        f4 acc = b0v;
        acc = MFMA(W0[1], hr0, acc);
        acc = MFMA(W0[2], hr1, acc);
        acc = MFMA(W0[0], xc,  acc);
        float h = elem(acc, c0);
        *(_Float16*)(lb + 0 * 2048 + wro) = (_Float16)h;
        __syncthreads();
    }

    // ---- it = 1..TT-1: L0(t=it) + L1(t=it-1), one barrier/step ----
    for (int it = 1; it < TT; ++it) {
        const int wp = it & 1, rp = wp ^ 1;
        h8 xc  = cvt8(xp + it * DIN);
        h8 hr0 = *(const h8*)(lb + rp * 2048 + rd0);          // h0[it-1]
        h8 hr1 = *(const h8*)(lb + rp * 2048 + rd1);
        h8 g1a = *(const h8*)(lb + 4096 + rp * 2048 + rd0);   // h1[it-2]
        h8 g1b = *(const h8*)(lb + 4096 + rp * 2048 + rd1);

        // MFMA cluster (L0 + L1 together), then both elems
        f4 a0 = b0v;
        a0 = MFMA(W0[1], hr0, a0);
        a0 = MFMA(W0[2], hr1, a0);
        a0 = MFMA(W0[0], xc,  a0);
        f4 a1 = b1v;
        a1 = MFMA(W1[0], hr0, a1);
        a1 = MFMA(W1[1], hr1, a1);
        a1 = MFMA(W1[2], g1a, a1);
        a1 = MFMA(W1[3], g1b, a1);

        float h0 = elem(a0, c0);
        float h1 = elem(a1, c1);
        h1f = h1;
        *(_Float16*)(lb + wp * 2048 + wro) = (_Float16)h0;
        *(_Float16*)(lb + 4096 + wp * 2048 + wro) = (_Float16)h1;
        __syncthreads();
    }

    // ---- tail: L1 for t = TT-1 (reads parity 1) ----
    {
        h8 hr0 = *(const h8*)(lb + 2048 + rd0);              // h0[TT-1]
        h8 hr1 = *(const h8*)(lb + 2048 + rd1);
        h8 g1a = *(const h8*)(lb + 4096 + 2048 + rd0);       // h1[TT-2]
        h8 g1b = *(const h8*)(lb + 4096 + 2048 + rd1);
        f4 a1 = b1v;
        a1 = MFMA(W1[0], hr0, a1);
        a1 = MFMA(W1[1], hr1, a1);
        a1 = MFMA(W1[2], g1a, a1);
        a1 = MFMA(W1[3], g1b, a1);
        h1f = elem(a1, c1);
    }

    // ---- head: out[b] = h1 . fc_w + fc_b ----
    float part = h1f * fcw[4 * wv + kg];
    part += __shfl_xor(part, 16, 64);
    part += __shfl_xor(part, 32, 64);
    if (lane < 16) wpart[wv][lane] = part;
    __syncthreads();
    if (tid < BT) {
        float s = fcb[0];
        #pragma unroll
        for (int w = 0; w < 16; ++w) s += wpart[w][tid];
        out[bbase + tid] = s;
    }
}

extern "C" void kernel_launch(void* const* d_in, const int* in_sizes, int n_in,
                              void* d_out, int out_size, void* d_ws, size_t ws_size,
                              hipStream_t stream) {
    (void)in_sizes; (void)n_in; (void)d_ws; (void)ws_size; (void)out_size;
    lstm2_fused<<<dim3(8192 / BT), dim3(1024), 0, stream>>>(
        (const float*)d_in[0],
        (const float*)d_in[1], (const float*)d_in[2],
        (const float*)d_in[3], (const float*)d_in[4],
        (const float*)d_in[5], (const float*)d_in[6],
        (const float*)d_in[7], (const float*)d_in[8],
        (const float*)d_in[9], (const float*)d_in[10],
        (float*)d_out);
}

// Round 14
// 185.497 us; speedup vs baseline: 1.8506x; 1.8506x over previous
//
#include <hip/hip_runtime.h>

// 2-layer fused LSTM + linear head.  B=8192, T=128, D=32, H=64, gates=256.
// R14: FAT WAVES — 256 thr / 4 waves, BT=16, grid 512 (2 blocks/CU,
// 2 waves/SIMD).  Wave wv owns h-slice [16wv,16wv+16) = 4 gate-interleaved
// row-tiles per layer: 28 MFMA + 8 elems/lane/step.
// Rationale: wall/step = VALU 2264cy (65%) + LDS-read burst ~770cy + chain
// ~400cy.  LDS burst scales with WAVES (each re-reads the same 4KB h-state):
// 16 waves/CU (R4..R11) = 64KB/step; 4-wave blocks halve it to 32KB.  Total
// VALU unchanged; per-wave elem ILP doubles (8 independent trans chains feed
// the VALU from within one wave).  R3 tested this shape with unoptimized
// math (10 trans, no clustering); this is the first fair test.
// D-layout per tile: element r of lane (bl,kg) = gate r of h = hbase+kg.
// log2e folded into weights (i,f,o x1.4427; g x2.8854); merged-rcp gate math
// = 5 exp2 + 2 rcp = 7 hw trans/element (R8: poly is worse).

#define TT  128
#define DIN 32
#define BT  16
#define L2E 1.44269504088896340736f

typedef _Float16 h8 __attribute__((ext_vector_type(8)));
typedef __fp16   p2 __attribute__((ext_vector_type(2)));
typedef float    f4 __attribute__((ext_vector_type(4)));

#define MFMA(A, B, C) __builtin_amdgcn_mfma_f32_16x16x32_f16((A), (B), (C), 0, 0, 0)

__device__ __forceinline__ h8 cvt8s(const float* p, float s) {
    float4 a = *(const float4*)p;
    float4 b = *(const float4*)(p + 4);
    union { h8 v; p2 q[4]; } u;
    u.q[0] = __builtin_amdgcn_cvt_pkrtz(a.x * s, a.y * s);
    u.q[1] = __builtin_amdgcn_cvt_pkrtz(a.z * s, a.w * s);
    u.q[2] = __builtin_amdgcn_cvt_pkrtz(b.x * s, b.y * s);
    u.q[3] = __builtin_amdgcn_cvt_pkrtz(b.z * s, b.w * s);
    return u.v;
}

__device__ __forceinline__ h8 pack8(const float4& a, const float4& b) {
    union { h8 v; p2 q[4]; } u;
    u.q[0] = __builtin_amdgcn_cvt_pkrtz(a.x, a.y);
    u.q[1] = __builtin_amdgcn_cvt_pkrtz(a.z, a.w);
    u.q[2] = __builtin_amdgcn_cvt_pkrtz(b.x, b.y);
    u.q[3] = __builtin_amdgcn_cvt_pkrtz(b.z, b.w);
    return u.v;
}

// acc = {yi', yf', yg'(2x-scaled), yo'} (log2e pre-folded); updates c, returns h.
__device__ __forceinline__ float elem(const f4& acc, float& c) {
    float Ei = __builtin_amdgcn_exp2f(-acc[0]);
    float Ef = __builtin_amdgcn_exp2f(-acc[1]);
    float Eg = __builtin_amdgcn_exp2f(-acc[2]);
    float Eo = __builtin_amdgcn_exp2f(-acc[3]);
    float a = 1.f + Ei, b = 1.f + Eg, d = 1.f + Ef;
    float P = a * b;
    float N = c * P + (1.f - Eg) * d;
    c = N * __builtin_amdgcn_rcpf(P * d);
    float Ec = __builtin_amdgcn_exp2f(-2.f * L2E * c);
    return (1.f - Ec) * __builtin_amdgcn_rcpf((1.f + Ec) * (1.f + Eo));
}

__global__ __launch_bounds__(256, 2)
void lstm2_fused(const float* __restrict__ x,
                 const float* __restrict__ wih0, const float* __restrict__ whh0,
                 const float* __restrict__ bih0, const float* __restrict__ bhh0,
                 const float* __restrict__ wih1, const float* __restrict__ whh1,
                 const float* __restrict__ bih1, const float* __restrict__ bhh1,
                 const float* __restrict__ fcw,  const float* __restrict__ fcb,
                 float* __restrict__ out)
{
    const int tid  = threadIdx.x;
    const int lane = tid & 63;
    const int wv   = tid >> 6;      // 0..3 -> h slice [16wv, 16wv+16)
    const int bl   = lane & 15;
    const int kg   = lane >> 4;

    __shared__ alignas(16) unsigned short hb[2][2][BT * 64];  // 8 KB
    __shared__ float wpart[4][BT];

    for (int i = tid; i < (int)(sizeof(hb) / 4); i += 256) ((int*)hb)[i] = 0;

    // ---- weights: 4 gate-interleaved row tiles per layer, log2e folded ----
    h8 W0[4][3], W1[4][4];
    f4 b0v[4], b1v[4];
    int wro[4];
    const int swz = (bl & 7) << 4;
    const int rowoff = bl * 128;
    #pragma unroll
    for (int t = 0; t < 4; ++t) {
        const int hbse = 16 * wv + 4 * t;
        const int gam  = bl & 3;                         // gate of this A-row
        const int g    = 64 * gam + hbse + (bl >> 2);    // global weight row
        const float sc = (gam == 2) ? 2.f * L2E : L2E;
        W0[t][0] = cvt8s(wih0 + g * 32 + 8 * kg, sc);
        W0[t][1] = cvt8s(whh0 + g * 64 + 8 * kg, sc);
        W0[t][2] = cvt8s(whh0 + g * 64 + 32 + 8 * kg, sc);
        W1[t][0] = cvt8s(wih1 + g * 64 + 8 * kg, sc);
        W1[t][1] = cvt8s(wih1 + g * 64 + 32 + 8 * kg, sc);
        W1[t][2] = cvt8s(whh1 + g * 64 + 8 * kg, sc);
        W1[t][3] = cvt8s(whh1 + g * 64 + 32 + 8 * kg, sc);
        #pragma unroll
        for (int r = 0; r < 4; ++r) {
            const int gr = 64 * r + hbse + kg;           // D element r = gate r of h=hbse+kg
            const float scr = (r == 2) ? 2.f * L2E : L2E;
            b0v[t][r] = (bih0[gr] + bhh0[gr]) * scr;
            b1v[t][r] = (bih1[gr] + bhh1[gr]) * scr;
        }
        wro[t] = rowoff + ((32 * wv + 8 * t + 2 * kg) ^ swz);  // h = hbse+kg
    }

    const int bbase = blockIdx.x * BT;
    const float* xp = x + (size_t)(bbase + bl) * (TT * DIN) + 8 * kg;

    float c0[4] = {0.f, 0.f, 0.f, 0.f};
    float c1[4] = {0.f, 0.f, 0.f, 0.f};
    float h1f[4] = {0.f, 0.f, 0.f, 0.f};

    __syncthreads();   // LDS zero visible

    char* lb = (char*)hb;
    const int rd0 = rowoff + ((16 * kg) ^ swz);
    const int rd1 = rowoff + ((64 + 16 * kg) ^ swz);

    h8 xcur;

    // One skewed step: {L0[it], L1[it-1]}; 28-MFMA cluster, then 8 elems.
    auto STEP = [&](int wp, int rp, const float* xnext) {
        float4 xnA, xnB;
        if (xnext) { xnA = *(const float4*)xnext; xnB = *(const float4*)(xnext + 4); }

        h8 hr0 = *(const h8*)(lb + rp * 2048 + rd0);          // h0[it-1]
        h8 hr1 = *(const h8*)(lb + rp * 2048 + rd1);
        h8 g1a = *(const h8*)(lb + 4096 + rp * 2048 + rd0);   // h1[it-2]
        h8 g1b = *(const h8*)(lb + 4096 + rp * 2048 + rd1);

        f4 a0[4], a1[4];
        #pragma unroll
        for (int k = 0; k < 4; ++k) {
            a0[k] = b0v[k];
            a0[k] = MFMA(W0[k][1], hr0, a0[k]);
            a0[k] = MFMA(W0[k][2], hr1, a0[k]);
            a0[k] = MFMA(W0[k][0], xcur, a0[k]);
        }
        #pragma unroll
        for (int k = 0; k < 4; ++k) {
            a1[k] = b1v[k];
            a1[k] = MFMA(W1[k][0], hr0, a1[k]);
            a1[k] = MFMA(W1[k][1], hr1, a1[k]);
            a1[k] = MFMA(W1[k][2], g1a, a1[k]);
            a1[k] = MFMA(W1[k][3], g1b, a1[k]);
        }

        #pragma unroll
        for (int k = 0; k < 4; ++k) {
            float h = elem(a0[k], c0[k]);
            *(_Float16*)(lb + wp * 2048 + wro[k]) = (_Float16)h;
        }
        #pragma unroll
        for (int k = 0; k < 4; ++k) {
            float h = elem(a1[k], c1[k]);
            h1f[k] = h;
            *(_Float16*)(lb + 4096 + wp * 2048 + wro[k]) = (_Float16)h;
        }

        if (xnext) xcur = pack8(xnA, xnB);
        __syncthreads();
    };

    // ---- it = 0: L0 only (t=0); h0[-1]=0 from zeroed parity-1 buffer ----
    {
        float4 x0a = *(const float4*)(xp);
        float4 x0b = *(const float4*)(xp + 4);
        float4 xnA = *(const float4*)(xp + DIN);       // prefetch x[1]
        float4 xnB = *(const float4*)(xp + DIN + 4);
        h8 xc  = pack8(x0a, x0b);
        h8 hr0 = *(const h8*)(lb + 2048 + rd0);
        h8 hr1 = *(const h8*)(lb + 2048 + rd1);
        f4 a0[4];
        #pragma unroll
        for (int k = 0; k < 4; ++k) {
            a0[k] = b0v[k];
            a0[k] = MFMA(W0[k][1], hr0, a0[k]);
            a0[k] = MFMA(W0[k][2], hr1, a0[k]);
            a0[k] = MFMA(W0[k][0], xc, a0[k]);
        }
        #pragma unroll
        for (int k = 0; k < 4; ++k) {
            float h = elem(a0[k], c0[k]);
            *(_Float16*)(lb + 0 * 2048 + wro[k]) = (_Float16)h;
        }
        xcur = pack8(xnA, xnB);
        __syncthreads();
    }

    // ---- it = 1..126 unrolled x2 (parities literal), then peel it=127 ----
    for (int itp = 1; itp < TT - 1; itp += 2) {
        STEP(1, 0, xp + (itp + 1) * DIN);   // it = itp   (odd)
        STEP(0, 1, xp + (itp + 2) * DIN);   // it = itp+1 (even)
    }
    STEP(1, 0, nullptr);                    // it = 127

    // ---- tail: L1 for t = TT-1 (reads parity 1) ----
    {
        h8 hr0 = *(const h8*)(lb + 2048 + rd0);              // h0[127]
        h8 hr1 = *(const h8*)(lb + 2048 + rd1);
        h8 g1a = *(const h8*)(lb + 4096 + 2048 + rd0);       // h1[126]
        h8 g1b = *(const h8*)(lb + 4096 + 2048 + rd1);
        #pragma unroll
        for (int k = 0; k < 4; ++k) {
            f4 a1 = b1v[k];
            a1 = MFMA(W1[k][0], hr0, a1);
            a1 = MFMA(W1[k][1], hr1, a1);
            a1 = MFMA(W1[k][2], g1a, a1);
            a1 = MFMA(W1[k][3], g1b, a1);
            h1f[k] = elem(a1, c1[k]);
        }
    }

    // ---- head: out[b] = h1 . fc_w + fc_b ----
    float part = 0.f;
    #pragma unroll
    for (int k = 0; k < 4; ++k) part += h1f[k] * fcw[16 * wv + 4 * k + kg];
    part += __shfl_xor(part, 16, 64);
    part += __shfl_xor(part, 32, 64);
    if (lane < 16) wpart[wv][lane] = part;
    __syncthreads();
    if (tid < BT)
        out[bbase + tid] = wpart[0][tid] + wpart[1][tid] + wpart[2][tid] + wpart[3][tid] + fcb[0];
}

extern "C" void kernel_launch(void* const* d_in, const int* in_sizes, int n_in,
                              void* d_out, int out_size, void* d_ws, size_t ws_size,
                              hipStream_t stream) {
    (void)in_sizes; (void)n_in; (void)d_ws; (void)ws_size; (void)out_size;
    lstm2_fused<<<dim3(8192 / BT), dim3(256), 0, stream>>>(
        (const float*)d_in[0],
        (const float*)d_in[1], (const float*)d_in[2],
        (const float*)d_in[3], (const float*)d_in[4],
        (const float*)d_in[5], (const float*)d_in[6],
        (const float*)d_in[7], (const float*)d_in[8],
        (const float*)d_in[9], (const float*)d_in[10],
        (float*)d_out);
}

// Round 15
// 175.837 us; speedup vs baseline: 1.9523x; 1.0549x over previous
//
#include <hip/hip_runtime.h>

// 2-layer fused LSTM + linear head.  B=8192, T=128, D=32, H=64, gates=256.
// R15 = R11 (1024 thr / 16 waves, BT=32, grid 256 -> 1 block/CU, single
// barrier domain, MFMA cluster + setprio, x prefetch) + PACKED-F32 elem:
// the two elems per lane per layer are processed pairwise on float2
// ext-vectors so the ~14 full-rate ops/elem become v_pk_*_f32 (VOP3P,
// gfx90a+), halving non-trans VALU issue (~470 -> ~240 cy/SIMD/step).
// Trans (5 exp2 + 2 rcp per elem, hw ops) unchanged — that's the floor.
// Wave wv -> batch-half bh=wv>>3, h-block hw=wv&7 (h in [8hw,8hw+8)).
// log2e folded into weights (i,f,o x1.4427; g x2.8854); merged-rcp gate math.

#define TT  128
#define DIN 32
#define BT  32
#define L2E 1.44269504088896340736f

typedef _Float16 h8 __attribute__((ext_vector_type(8)));
typedef __fp16   p2 __attribute__((ext_vector_type(2)));
typedef float    f4 __attribute__((ext_vector_type(4)));
typedef float    f2 __attribute__((ext_vector_type(2)));

#define MFMA(A, B, C) __builtin_amdgcn_mfma_f32_16x16x32_f16((A), (B), (C), 0, 0, 0)

__device__ __forceinline__ h8 cvt8s(const float* p, float s) {
    float4 a = *(const float4*)p;
    float4 b = *(const float4*)(p + 4);
    union { h8 v; p2 q[4]; } u;
    u.q[0] = __builtin_amdgcn_cvt_pkrtz(a.x * s, a.y * s);
    u.q[1] = __builtin_amdgcn_cvt_pkrtz(a.z * s, a.w * s);
    u.q[2] = __builtin_amdgcn_cvt_pkrtz(b.x * s, b.y * s);
    u.q[3] = __builtin_amdgcn_cvt_pkrtz(b.z * s, b.w * s);
    return u.v;
}

__device__ __forceinline__ h8 pack8(const float4& a, const float4& b) {
    union { h8 v; p2 q[4]; } u;
    u.q[0] = __builtin_amdgcn_cvt_pkrtz(a.x, a.y);
    u.q[1] = __builtin_amdgcn_cvt_pkrtz(a.z, a.w);
    u.q[2] = __builtin_amdgcn_cvt_pkrtz(b.x, b.y);
    u.q[3] = __builtin_amdgcn_cvt_pkrtz(b.z, b.w);
    return u.v;
}

// Pairwise elem: A,B = gate accs {yi',yf',yg'(2x),yo'} of two h-elements
// (log2e pre-folded).  c = their cell states (f2).  Returns {hA, hB}.
// Trans ops stay scalar (8 exp2 + 4 rcp); all algebra is float2 -> VOP3P.
__device__ __forceinline__ f2 elem2(const f4& A, const f4& B, f2& c) {
    f2 Ei = { __builtin_amdgcn_exp2f(-A[0]), __builtin_amdgcn_exp2f(-B[0]) };
    f2 Ef = { __builtin_amdgcn_exp2f(-A[1]), __builtin_amdgcn_exp2f(-B[1]) };
    f2 Eg = { __builtin_amdgcn_exp2f(-A[2]), __builtin_amdgcn_exp2f(-B[2]) };
    f2 Eo = { __builtin_amdgcn_exp2f(-A[3]), __builtin_amdgcn_exp2f(-B[3]) };
    const f2 one = {1.f, 1.f};
    f2 a = one + Ei, b = one + Eg, d = one + Ef;
    f2 P = a * b;
    f2 N = c * P + (one - Eg) * d;
    f2 Pd = P * d;
    f2 rPd = { __builtin_amdgcn_rcpf(Pd[0]), __builtin_amdgcn_rcpf(Pd[1]) };
    c = N * rPd;
    f2 Ec = { __builtin_amdgcn_exp2f(-2.f * L2E * c[0]),
              __builtin_amdgcn_exp2f(-2.f * L2E * c[1]) };
    f2 q = (one + Ec) * (one + Eo);
    f2 rq = { __builtin_amdgcn_rcpf(q[0]), __builtin_amdgcn_rcpf(q[1]) };
    return (one - Ec) * rq;
}

__global__ __launch_bounds__(1024, 4)
void lstm2_fused(const float* __restrict__ x,
                 const float* __restrict__ wih0, const float* __restrict__ whh0,
                 const float* __restrict__ bih0, const float* __restrict__ bhh0,
                 const float* __restrict__ wih1, const float* __restrict__ whh1,
                 const float* __restrict__ bih1, const float* __restrict__ bhh1,
                 const float* __restrict__ fcw,  const float* __restrict__ fcb,
                 float* __restrict__ out)
{
    const int tid  = threadIdx.x;
    const int lane = tid & 63;
    const int wv   = tid >> 6;      // 0..15
    const int hw   = wv & 7;        // h block 8*hw
    const int bh   = wv >> 3;       // batch half 0/1
    const int bl   = lane & 15;
    const int kg   = lane >> 4;

    // [layer][parity][b (32 rows)][h (64)] f16, XOR-swizzled; 16 KB
    __shared__ alignas(16) unsigned short hb[2][2][BT * 64];
    __shared__ float wpart[16][16];

    for (int i = tid; i < (int)(sizeof(hb) / 4); i += 1024) ((int*)hb)[i] = 0;

    // ---- weights: gate-interleaved row tiles, log2e folded ----
    h8 W0[2][3], W1[2][4];
    f4 b0v[2], b1v[2];
    #pragma unroll
    for (int t = 0; t < 2; ++t) {
        const int hbse = 8 * hw + 4 * t;
        const int gam  = bl & 3;                         // gate of this A-row
        const int g    = 64 * gam + hbse + (bl >> 2);    // global weight row
        const float sc = (gam == 2) ? 2.f * L2E : L2E;
        W0[t][0] = cvt8s(wih0 + g * 32 + 8 * kg, sc);
        W0[t][1] = cvt8s(whh0 + g * 64 + 8 * kg, sc);
        W0[t][2] = cvt8s(whh0 + g * 64 + 32 + 8 * kg, sc);
        W1[t][0] = cvt8s(wih1 + g * 64 + 8 * kg, sc);
        W1[t][1] = cvt8s(wih1 + g * 64 + 32 + 8 * kg, sc);
        W1[t][2] = cvt8s(whh1 + g * 64 + 8 * kg, sc);
        W1[t][3] = cvt8s(whh1 + g * 64 + 32 + 8 * kg, sc);
        #pragma unroll
        for (int r = 0; r < 4; ++r) {
            const int gr = 64 * r + hbse + kg;           // D element r = gate r of h=hbse+kg
            const float scr = (r == 2) ? 2.f * L2E : L2E;
            b0v[t][r] = (bih0[gr] + bhh0[gr]) * scr;
            b1v[t][r] = (bih1[gr] + bhh1[gr]) * scr;
        }
    }

    const int bbase = blockIdx.x * BT;
    const int brow  = 16 * bh + bl;                      // batch row within block
    const float* xp = x + (size_t)(bbase + brow) * (TT * DIN) + 8 * kg;

    f2 c0 = {0.f, 0.f}, c1 = {0.f, 0.f}, h1f = {0.f, 0.f};

    __syncthreads();   // LDS zero visible

    const int swz = (brow & 7) << 4;
    char* lb = (char*)hb;
    const int rowoff = brow * 128;
    const int rd0 = rowoff + ((16 * kg) ^ swz);
    const int rd1 = rowoff + ((64 + 16 * kg) ^ swz);
    const int wro0 = rowoff + ((16 * hw + 2 * kg) ^ swz);        // h = 8hw+kg   (t=0)
    const int wro1 = rowoff + ((16 * hw + 8 + 2 * kg) ^ swz);    // h = 8hw+4+kg (t=1)

    h8 xcur;

    // One skewed step: {L0[it], L1[it-1]}; MFMA cluster first, then elems.
    // Parity regions: 4096 B (2 parity x 32 rows x 128 B per layer).
    auto STEP = [&](int wp, int rp, const float* xnext) {
        float4 xnA, xnB;
        if (xnext) { xnA = *(const float4*)xnext; xnB = *(const float4*)(xnext + 4); }

        h8 hr0 = *(const h8*)(lb + rp * 4096 + rd0);          // h0[it-1]
        h8 hr1 = *(const h8*)(lb + rp * 4096 + rd1);
        h8 g1a = *(const h8*)(lb + 8192 + rp * 4096 + rd0);   // h1[it-2]
        h8 g1b = *(const h8*)(lb + 8192 + rp * 4096 + rd1);

        __builtin_amdgcn_s_setprio(1);
        f4 a00 = b0v[0];
        a00 = MFMA(W0[0][1], hr0, a00);
        a00 = MFMA(W0[0][2], hr1, a00);
        a00 = MFMA(W0[0][0], xcur, a00);
        f4 a01 = b0v[1];
        a01 = MFMA(W0[1][1], hr0, a01);
        a01 = MFMA(W0[1][2], hr1, a01);
        a01 = MFMA(W0[1][0], xcur, a01);
        f4 a10 = b1v[0];
        a10 = MFMA(W1[0][0], hr0, a10);
        a10 = MFMA(W1[0][1], hr1, a10);
        a10 = MFMA(W1[0][2], g1a, a10);
        a10 = MFMA(W1[0][3], g1b, a10);
        f4 a11 = b1v[1];
        a11 = MFMA(W1[1][0], hr0, a11);
        a11 = MFMA(W1[1][1], hr1, a11);
        a11 = MFMA(W1[1][2], g1a, a11);
        a11 = MFMA(W1[1][3], g1b, a11);
        __builtin_amdgcn_s_setprio(0);

        f2 h0p = elem2(a00, a01, c0);
        f2 h1p = elem2(a10, a11, c1);
        h1f = h1p;

        *(_Float16*)(lb + wp * 4096 + wro0) = (_Float16)h0p[0];
        *(_Float16*)(lb + wp * 4096 + wro1) = (_Float16)h0p[1];
        *(_Float16*)(lb + 8192 + wp * 4096 + wro0) = (_Float16)h1p[0];
        *(_Float16*)(lb + 8192 + wp * 4096 + wro1) = (_Float16)h1p[1];

        if (xnext) xcur = pack8(xnA, xnB);
        __syncthreads();
    };

    // ---- it = 0: L0 only (t=0); h0[-1]=0 from zeroed parity-1 buffer ----
    {
        float4 x0a = *(const float4*)(xp);
        float4 x0b = *(const float4*)(xp + 4);
        float4 xnA = *(const float4*)(xp + DIN);       // prefetch x[1]
        float4 xnB = *(const float4*)(xp + DIN + 4);
        h8 xc  = pack8(x0a, x0b);
        h8 hr0 = *(const h8*)(lb + 4096 + rd0);
        h8 hr1 = *(const h8*)(lb + 4096 + rd1);
        __builtin_amdgcn_s_setprio(1);
        f4 a00 = b0v[0];
        a00 = MFMA(W0[0][1], hr0, a00);
        a00 = MFMA(W0[0][2], hr1, a00);
        a00 = MFMA(W0[0][0], xc, a00);
        f4 a01 = b0v[1];
        a01 = MFMA(W0[1][1], hr0, a01);
        a01 = MFMA(W0[1][2], hr1, a01);
        a01 = MFMA(W0[1][0], xc, a01);
        __builtin_amdgcn_s_setprio(0);
        f2 h0p = elem2(a00, a01, c0);
        *(_Float16*)(lb + 0 * 4096 + wro0) = (_Float16)h0p[0];
        *(_Float16*)(lb + 0 * 4096 + wro1) = (_Float16)h0p[1];
        xcur = pack8(xnA, xnB);
        __syncthreads();
    }

    // ---- it = 1..126 unrolled x2 (parities literal), then peel it=127 ----
    for (int itp = 1; itp < TT - 1; itp += 2) {
        STEP(1, 0, xp + (itp + 1) * DIN);   // it = itp   (odd)
        STEP(0, 1, xp + (itp + 2) * DIN);   // it = itp+1 (even)
    }
    STEP(1, 0, nullptr);                    // it = 127

    // ---- tail: L1 for t = TT-1 (reads parity 1) ----
    {
        h8 hr0 = *(const h8*)(lb + 4096 + rd0);              // h0[127]
        h8 hr1 = *(const h8*)(lb + 4096 + rd1);
        h8 g1a = *(const h8*)(lb + 8192 + 4096 + rd0);       // h1[126]
        h8 g1b = *(const h8*)(lb + 8192 + 4096 + rd1);
        f4 a10 = b1v[0];
        a10 = MFMA(W1[0][0], hr0, a10);
        a10 = MFMA(W1[0][1], hr1, a10);
        a10 = MFMA(W1[0][2], g1a, a10);
        a10 = MFMA(W1[0][3], g1b, a10);
        f4 a11 = b1v[1];
        a11 = MFMA(W1[1][0], hr0, a11);
        a11 = MFMA(W1[1][1], hr1, a11);
        a11 = MFMA(W1[1][2], g1a, a11);
        a11 = MFMA(W1[1][3], g1b, a11);
        h1f = elem2(a10, a11, c1);
    }

    // ---- head: out[b] = h1 . fc_w + fc_b ----
    float part = h1f[0] * fcw[8 * hw + kg] + h1f[1] * fcw[8 * hw + 4 + kg];
    part += __shfl_xor(part, 16, 64);
    part += __shfl_xor(part, 32, 64);
    if (lane < 16) wpart[wv][lane] = part;
    __syncthreads();
    if (tid < BT) {
        const int tbh = tid >> 4, tbl = tid & 15;
        float s = fcb[0];
        #pragma unroll
        for (int w = 0; w < 8; ++w) s += wpart[8 * tbh + w][tbl];
        out[bbase + tid] = s;
    }
}

extern "C" void kernel_launch(void* const* d_in, const int* in_sizes, int n_in,
                              void* d_out, int out_size, void* d_ws, size_t ws_size,
                              hipStream_t stream) {
    (void)in_sizes; (void)n_in; (void)d_ws; (void)ws_size; (void)out_size;
    lstm2_fused<<<dim3(8192 / BT), dim3(1024), 0, stream>>>(
        (const float*)d_in[0],
        (const float*)d_in[1], (const float*)d_in[2],
        (const float*)d_in[3], (const float*)d_in[4],
        (const float*)d_in[5], (const float*)d_in[6],
        (const float*)d_in[7], (const float*)d_in[8],
        (const float*)d_in[9], (const float*)d_in[10],
        (float*)d_out);
}